// Round 11
// baseline (68.091 us; speedup 1.0000x reference)
//
#include <hip/hip_runtime.h>

#define N_NODES   100000
#define N_EDGES   3200000
#define D_FEAT    128

// ---- bin phase ----
#define B_TPB     1024
#define B_EPT     16
#define B_CHUNK   (B_TPB * B_EPT)     // 16384 edges/block
#define B_GRID    196                 // ceil(N_EDGES / B_CHUNK); last block 320 valid threads
#define TBL_SLICE 50000               // 2 passes x 100 KB LDS
#define N_PASSES  2
#define CAP       16384               // region capacity per (block, slice)

// ---- scatter phase ----
#define DSLICE    25000               // 4 dst slices; 100 KB f32 LDS accumulator
#define DSLICE4   (DSLICE / 4)        // 6250
#define N_DSLICES 4
#define NCHUNK    49                  // 4 * 49 = 196 scatter blocks; chunk c <- producers 4c..4c+3
#define S_TPB     1024

__device__ __forceinline__ unsigned short f2bf(float f) {
    union { float f; unsigned u; } c; c.f = f;
    unsigned r = c.u + 0x7FFFu + ((c.u >> 16) & 1u);
    return (unsigned short)(r >> 16);
}
__device__ __forceinline__ float bf2f(unsigned short h) {
    union { unsigned u; float f; } c; c.u = ((unsigned)h) << 16; return c.f;
}

// ---------------------------------------------------------------------------
// Kernel 1: per-node feature row-sum -> bf16 table.
// ---------------------------------------------------------------------------
__global__ void __launch_bounds__(256) rowsum_kernel(
    const float* __restrict__ feat,
    unsigned short* __restrict__ rowsum_bf)
{
    const int gid = (int)(blockIdx.x * blockDim.x + threadIdx.x);
    const int row = gid >> 5;
    const int sub = gid & 31;
    if (row >= N_NODES) return;

    const float4 v = reinterpret_cast<const float4*>(
        feat + (size_t)row * D_FEAT)[sub];
    float s = (v.x + v.y) + (v.z + v.w);

    #pragma unroll
    for (int off = 16; off > 0; off >>= 1)
        s += __shfl_xor(s, off, 64);

    if (sub == 0) rowsum_bf[row] = f2bf(s);
}

// ---------------------------------------------------------------------------
// Kernel 2: gather + bin. 16 edges/thread held in registers. rowsum table
// staged into LDS in 2 passes (100 KB); vals gathered via ds_read (no L1-miss
// path). Then per-edge dst-slice computed, wave-aggregated LDS counters give
// append offsets, and (dst_local<<16 | val) pairs go to per-(block,slice)
// global regions. Every expensive op issued exactly once per edge.
// ---------------------------------------------------------------------------
__global__ void __launch_bounds__(B_TPB) bin_kernel(
    const int* __restrict__ edge_src,
    const int* __restrict__ edge_dst,
    const unsigned short* __restrict__ rowsum_bf,
    unsigned int* __restrict__ regions,   // [B_GRID][4][CAP]
    int* __restrict__ counts)             // [B_GRID][4]
{
    __shared__ __align__(16) unsigned short tbl[TBL_SLICE];
    __shared__ unsigned int lc[4];

    const int tid  = (int)threadIdx.x;
    const int bid  = (int)blockIdx.x;
    const int lane = tid & 63;
    const int base = bid * B_CHUNK + tid * B_EPT;
    const bool v   = (base + B_EPT) <= N_EDGES;   // thread fully valid or not

    if (tid < 4) lc[tid] = 0;

    int4 s0={0,0,0,0}, s1={0,0,0,0}, s2={0,0,0,0}, s3={0,0,0,0};
    int4 d0={0,0,0,0}, d1={0,0,0,0}, d2={0,0,0,0}, d3={0,0,0,0};
    if (v) {
        s0 = *(const int4*)(edge_src + base);      d0 = *(const int4*)(edge_dst + base);
        s1 = *(const int4*)(edge_src + base + 4);  d1 = *(const int4*)(edge_dst + base + 4);
        s2 = *(const int4*)(edge_src + base + 8);  d2 = *(const int4*)(edge_dst + base + 8);
        s3 = *(const int4*)(edge_src + base + 12); d3 = *(const int4*)(edge_dst + base + 12);
    }

    unsigned short w0=0,w1=0,w2=0,w3=0,w4=0,w5=0,w6=0,w7=0;
    unsigned short w8=0,w9=0,w10=0,w11=0,w12=0,w13=0,w14=0,w15=0;

    #pragma unroll
    for (int p = 0; p < N_PASSES; ++p) {
        const int lo = p * TBL_SLICE;
        if (p) __syncthreads();            // prior pass's reads done
        // stage 100 KB: 6250 x uint4 (16B) coalesced
        for (int i = tid; i < TBL_SLICE / 8; i += B_TPB)
            reinterpret_cast<uint4*>(tbl)[i] =
                reinterpret_cast<const uint4*>(rowsum_bf + lo)[i];
        __syncthreads();

        #define G(SS, WW) { const unsigned j = (unsigned)((SS) - lo); \
                            if (j < (unsigned)TBL_SLICE) WW = tbl[j]; }
        G(s0.x,w0)  G(s0.y,w1)  G(s0.z,w2)  G(s0.w,w3)
        G(s1.x,w4)  G(s1.y,w5)  G(s1.z,w6)  G(s1.w,w7)
        G(s2.x,w8)  G(s2.y,w9)  G(s2.z,w10) G(s2.w,w11)
        G(s3.x,w12) G(s3.y,w13) G(s3.z,w14) G(s3.w,w15)
        #undef G
    }

    // per-thread slice counts
    unsigned c0=0,c1=0,c2=0,c3=0;
    if (v) {
        #define CNT(DD) { const unsigned s_ = (unsigned)(DD) / DSLICE; \
                          c0 += (s_==0); c1 += (s_==1); c2 += (s_==2); c3 += (s_==3); }
        CNT(d0.x) CNT(d0.y) CNT(d0.z) CNT(d0.w)
        CNT(d1.x) CNT(d1.y) CNT(d1.z) CNT(d1.w)
        CNT(d2.x) CNT(d2.y) CNT(d2.z) CNT(d2.w)
        CNT(d3.x) CNT(d3.y) CNT(d3.z) CNT(d3.w)
        #undef CNT
    }

    // wave-level inclusive scan + single atomic per wave per slice
    unsigned e0,e1,e2,e3, t0,t1,t2,t3;
    {
        unsigned inc;
        #define SCAN(C, E, T) inc = (C); \
            { _Pragma("unroll") \
              for (int d_ = 1; d_ < 64; d_ <<= 1) { \
                  unsigned t_ = (unsigned)__shfl_up((int)inc, d_, 64); \
                  if (lane >= d_) inc += t_; } } \
            E = inc - (C); T = (unsigned)__shfl((int)inc, 63, 64);
        SCAN(c0, e0, t0) SCAN(c1, e1, t1) SCAN(c2, e2, t2) SCAN(c3, e3, t3)
        #undef SCAN
    }
    unsigned wb0=0, wb1=0, wb2=0, wb3=0;
    if (lane == 63) {
        wb0 = atomicAdd(&lc[0], t0);
        wb1 = atomicAdd(&lc[1], t1);
        wb2 = atomicAdd(&lc[2], t2);
        wb3 = atomicAdd(&lc[3], t3);
    }
    wb0 = (unsigned)__shfl((int)wb0, 63, 64);
    wb1 = (unsigned)__shfl((int)wb1, 63, 64);
    wb2 = (unsigned)__shfl((int)wb2, 63, 64);
    wb3 = (unsigned)__shfl((int)wb3, 63, 64);

    unsigned o0 = wb0 + e0, o1 = wb1 + e1, o2 = wb2 + e2, o3 = wb3 + e3;

    unsigned int* __restrict__ rbase = regions + (size_t)bid * 4 * CAP;
    if (v) {
        #define APP(DD, WW) { \
            const unsigned s_ = (unsigned)(DD) / DSLICE; \
            const unsigned dl = (unsigned)(DD) - s_ * DSLICE; \
            const unsigned pr = (dl << 16) | (unsigned)(WW); \
            const unsigned off = (s_==0) ? o0 : (s_==1) ? o1 : (s_==2) ? o2 : o3; \
            rbase[(size_t)s_ * CAP + off] = pr; \
            o0 += (s_==0); o1 += (s_==1); o2 += (s_==2); o3 += (s_==3); }
        APP(d0.x,w0)  APP(d0.y,w1)  APP(d0.z,w2)  APP(d0.w,w3)
        APP(d1.x,w4)  APP(d1.y,w5)  APP(d1.z,w6)  APP(d1.w,w7)
        APP(d2.x,w8)  APP(d2.y,w9)  APP(d2.z,w10) APP(d2.w,w11)
        APP(d3.x,w12) APP(d3.y,w13) APP(d3.z,w14) APP(d3.w,w15)
        #undef APP
    }

    __syncthreads();
    if (tid < 4) counts[bid * 4 + tid] = (int)lc[tid];
}

// ---------------------------------------------------------------------------
// Kernel 3: binned scatter. Block (s,c) reads compacted pairs of slice s from
// producers 4c..4c+3 (streaming, all lanes active), ds_add into 100 KB LDS
// accumulator, flush bf16.
// ---------------------------------------------------------------------------
__global__ void __launch_bounds__(S_TPB) scatter_kernel(
    const unsigned int* __restrict__ regions,
    const int* __restrict__ counts,
    unsigned short* __restrict__ copies)  // [4][NCHUNK][DSLICE]
{
    __shared__ __align__(16) float acc[DSLICE];

    const int tid = (int)threadIdx.x;
    const int bid = (int)blockIdx.x;
    const int s   = bid / NCHUNK;          // 0..3
    const int c   = bid % NCHUNK;          // 0..48

    float4 z; z.x = z.y = z.z = z.w = 0.0f;
    for (int i = tid; i < DSLICE4; i += S_TPB)
        reinterpret_cast<float4*>(acc)[i] = z;
    __syncthreads();

    #pragma unroll
    for (int pp = 0; pp < 4; ++pp) {
        const int p = c * 4 + pp;
        const int n = counts[p * 4 + s];
        const unsigned int* __restrict__ rb =
            regions + ((size_t)p * 4 + s) * CAP;
        for (int i = tid; i < n; i += S_TPB) {
            const unsigned pr = rb[i];
            atomicAdd(&acc[pr >> 16], bf2f((unsigned short)(pr & 0xFFFFu)));
        }
    }
    __syncthreads();

    unsigned short* __restrict__ dstp = copies + ((size_t)s * NCHUNK + c) * DSLICE;
    for (int i = tid; i < DSLICE4; i += S_TPB) {
        const float4 vv = reinterpret_cast<const float4*>(acc)[i];
        ushort4 o;
        o.x = f2bf(vv.x); o.y = f2bf(vv.y); o.z = f2bf(vv.z); o.w = f2bf(vv.w);
        reinterpret_cast<ushort4*>(dstp)[i] = o;
    }
}

// ---------------------------------------------------------------------------
// Kernel 4: reduce NCHUNK bf16 copies per slice + activations + int cast.
// ---------------------------------------------------------------------------
__global__ void __launch_bounds__(256) reduce_final_kernel(
    const unsigned short* __restrict__ copies,
    int* __restrict__ out)
{
    const int gid = (int)(blockIdx.x * blockDim.x + threadIdx.x);  // ushort4 unit
    if (gid >= N_NODES / 4) return;

    const int s  = gid / DSLICE4;
    const int j4 = gid - s * DSLICE4;

    float ax = 0.0f, ay = 0.0f, az = 0.0f, aw = 0.0f;
    const ushort4* base = reinterpret_cast<const ushort4*>(copies)
                        + (size_t)s * NCHUNK * DSLICE4 + j4;
    #pragma unroll 7
    for (int c = 0; c < NCHUNK; ++c) {
        const ushort4 vv = base[(size_t)c * DSLICE4];
        ax += bf2f(vv.x); ay += bf2f(vv.y); az += bf2f(vv.z); aw += bf2f(vv.w);
    }

    auto act = [](float x) -> int {
        const float a1 = (x  > 0.0f) ? x  : 0.1f * x;
        const float r2 = 16.0f * a1;
        const float a2 = (r2 > 0.0f) ? r2 : 0.1f * r2;
        return (int)(10.0f * a2);
    };

    int4 o;
    o.x = act(ax); o.y = act(ay); o.z = act(az); o.w = act(aw);
    reinterpret_cast<int4*>(out)[gid] = o;
}

extern "C" void kernel_launch(void* const* d_in, const int* in_sizes, int n_in,
                              void* d_out, int out_size, void* d_ws, size_t ws_size,
                              hipStream_t stream)
{
    const float* feat     = (const float*)d_in[0];
    const int*   edge_src = (const int*)d_in[1];
    const int*   edge_dst = (const int*)d_in[2];
    int*         out      = (int*)d_out;

    char* ws = (char*)d_ws;
    unsigned short* rowsum_bf = (unsigned short*)(ws);                 // 200 KB
    int*            counts    = (int*)(ws + (256 << 10));              // 3.1 KB
    unsigned int*   regions   = (unsigned int*)(ws + (320 << 10));     // 51.4 MB
    unsigned short* copies    = (unsigned short*)(ws + (320 << 10)
                                  + (size_t)B_GRID * 4 * CAP * 4);     // 9.8 MB

    // Kernel 1: rowsum -> bf16 table
    {
        const int threads = 256;
        const long long total = (long long)N_NODES * 32;
        const int blocks = (int)((total + threads - 1) / threads);
        rowsum_kernel<<<blocks, threads, 0, stream>>>(feat, rowsum_bf);
    }

    // Kernel 2: gather + bin (196 blocks, 2-pass LDS-staged table)
    bin_kernel<<<B_GRID, B_TPB, 0, stream>>>(edge_src, edge_dst, rowsum_bf,
                                             regions, counts);

    // Kernel 3: binned scatter (4 slices x 49 chunks)
    scatter_kernel<<<N_DSLICES * NCHUNK, S_TPB, 0, stream>>>(regions, counts,
                                                             copies);

    // Kernel 4: reduce + activations + int cast
    {
        const int threads = 256;
        const int blocks = (N_NODES / 4 + threads - 1) / threads;
        reduce_final_kernel<<<blocks, threads, 0, stream>>>(copies, out);
    }
}